// Round 1
// baseline (1275.527 us; speedup 1.0000x reference)
//
#include <hip/hip_runtime.h>
#include <stdint.h>

#define BATCH 4
#define NPTS 8192
#define CC 64
#define KNN_K 16
#define CAP 224
#define NHALF 4096

// ---------------------------------------------------------------- K0: prep
// cand[i] = (-2x, -2y, -2z, sq)  with sq = fmaf(z,z,fmaf(y,y,x*x))
__global__ __launch_bounds__(256) void k_prep(const float4* __restrict__ xytp,
                                              float4* __restrict__ cand) {
  int i = blockIdx.x * 256 + threadIdx.x;
  float4 p = xytp[i];
  float sq = fmaf(p.z, p.z, fmaf(p.y, p.y, p.x * p.x));
  cand[i] = make_float4(-2.f * p.x, -2.f * p.y, -2.f * p.z, sq);
}

// ---------------------------------------------------------------- K1: knn
// block = 128 threads (2 waves). 64 queries/block, each wave scans half the
// candidates. Query-per-lane. Approx scan keeps 4 chains x 4 (16 kept values;
// max(kept16) >= true 16th-smallest at all times), margin-gated append of
// candidate ids to LDS, exact (d2, idx)-lexicographic selection afterwards,
// then 2-wave merge.
__global__ __launch_bounds__(128) void k_knn(const float4* __restrict__ cand,
                                             int* __restrict__ oidx) {
  __shared__ __align__(16) unsigned short s_app[2][64][CAP];  // 57344 B
  const int lane = threadIdx.x & 63;
  const int wave = threadIdx.x >> 6;
  const int qg = blockIdx.x & 127;   // N/64 = 128
  const int b = blockIdx.x >> 7;
  const int n = (qg << 6) + lane;
  const float4* __restrict__ cb = cand + (b << 13);

  float4 cq = cb[n];
  const float qx = -0.5f * cq.x, qy = -0.5f * cq.y, qz = -0.5f * cq.z;
  const float qsq = cq.w;

  float ch[4][4];
#pragma unroll
  for (int m = 0; m < 4; ++m)
#pragma unroll
    for (int p = 0; p < 4; ++p) ch[m][p] = INFINITY;
  float gmax = INFINITY;
  int cnt = 0;
  bool ovf = false;

  const int j0 = __builtin_amdgcn_readfirstlane(wave * NHALF);
  for (int t = 0; t < NHALF; t += 4) {
#pragma unroll
    for (int m = 0; m < 4; ++m) {
      float4 A = cb[j0 + t + m];  // uniform -> s_load
      float d = fmaf(A.x, qx, A.w);
      d = fmaf(A.y, qy, d);
      d = fmaf(A.z, qz, d);
      if (d < gmax + 0.01f) {
        if (cnt < CAP) {
          s_app[wave][lane][cnt] = (unsigned short)(j0 + t + m);
          cnt++;
        } else {
          ovf = true;
        }
        float x = d;
#pragma unroll
        for (int p = 0; p < 4; ++p) {
          float lo = fminf(x, ch[m][p]);
          float hi = fmaxf(x, ch[m][p]);
          ch[m][p] = lo;
          x = hi;
        }
        gmax = fmaxf(fmaxf(ch[0][3], ch[1][3]), fmaxf(ch[2][3], ch[3][3]));
      }
    }
  }

  // exact selection: top-16 by (d2, idx) lexicographic, u64 keys
  unsigned long long lst[16];
#pragma unroll
  for (int p = 0; p < 16; ++p) lst[p] = ~0ULL;

  if (ovf) {
    // essentially-never fallback: exact rescan of this wave's half
    for (int j = j0; j < j0 + NHALF; ++j) {
      float4 A = cb[j];
      float xj = -0.5f * A.x, yj = -0.5f * A.y, zj = -0.5f * A.z;
      float dot = qx * xj;
      dot = fmaf(qy, yj, dot);
      dot = fmaf(qz, zj, dot);
      float d2 = (qsq + A.w) - 2.0f * dot;
      unsigned u = __float_as_uint(d2);
      u ^= (0x80000000u | (unsigned)((int)u >> 31));
      unsigned long long key = ((unsigned long long)u << 32) | (unsigned)j;
      if (key < lst[15]) {
        unsigned long long x = key;
#pragma unroll
        for (int p = 0; p < 16; ++p) {
          bool sw = x < lst[p];
          unsigned long long a = lst[p];
          lst[p] = sw ? x : a;
          x = sw ? a : x;
        }
      }
    }
  } else {
    for (int e = 0; e < cnt; ++e) {
      int j = s_app[wave][lane][e];
      float4 A = cb[j];  // divergent -> vector load (L1/L2 hit)
      float xj = -0.5f * A.x, yj = -0.5f * A.y, zj = -0.5f * A.z;
      float dot = qx * xj;
      dot = fmaf(qy, yj, dot);
      dot = fmaf(qz, zj, dot);
      float d2 = (qsq + A.w) - 2.0f * dot;
      unsigned u = __float_as_uint(d2);
      u ^= (0x80000000u | (unsigned)((int)u >> 31));
      unsigned long long key = ((unsigned long long)u << 32) | (unsigned)j;
      if (key < lst[15]) {
        unsigned long long x = key;
#pragma unroll
        for (int p = 0; p < 16; ++p) {
          bool sw = x < lst[p];
          unsigned long long a = lst[p];
          lst[p] = sw ? x : a;
          x = sw ? a : x;
        }
      }
    }
  }

  __syncthreads();  // appends fully consumed; reuse s_app as key buffer
  unsigned long long* kb = (unsigned long long*)&s_app[0][0][0];
  unsigned long long* mine = kb + ((wave << 6) + lane) * 17;
#pragma unroll
  for (int p = 0; p < 16; ++p) mine[p] = lst[p];
  mine[16] = ~0ULL;
  __syncthreads();

  if (wave == 0) {
    unsigned long long* A = kb + lane * 17;
    unsigned long long* B = kb + (64 + lane) * 17;
    int pa = 0, pb = 0;
    unsigned long long ka = A[0], kv = B[0];
    const int obase = (((b << 13) + n) << 4);
#pragma unroll
    for (int k = 0; k < 16; ++k) {
      bool ta = ka < kv;
      unsigned long long sel = ta ? ka : kv;
      oidx[obase + k] = (int)(unsigned)(sel & 0xFFFFFFFFull);
      if (ta) {
        ++pa;
        ka = A[pa];
      } else {
        ++pb;
        kv = B[pb];
      }
    }
  }
}

// ---------------------------------------------------------------- K2: lt = feat @ lt_w + lt_b
// block 256, 32 rows x 192 cols, fp32, LDS staged.
__global__ __launch_bounds__(256) void k_lt(const float* __restrict__ feat,
                                            const float* __restrict__ ltw,
                                            const float* __restrict__ ltb,
                                            float* __restrict__ lt) {
  __shared__ float sw[64][196];  // 50176 B (196 = 4*49, float4-aligned rows)
  __shared__ float sf[32][68];   // 8704 B
  const int tid = threadIdx.x;
  const int r0 = blockIdx.x * 32;
#pragma unroll
  for (int i = 0; i < 12; ++i) {
    int v = tid + i * 256;  // 0..3071 float4s
    float4 w4 = ((const float4*)ltw)[v];
    int row = (v * 4) / 192, col = (v * 4) % 192;
    *(float4*)&sw[row][col] = w4;
  }
#pragma unroll
  for (int i = 0; i < 2; ++i) {
    int v = tid + i * 256;  // 0..511 float4s
    int row = v >> 4, c4 = v & 15;
    float4 f4 = ((const float4*)(feat + (size_t)(r0 + row) * 64))[c4];
    *(float4*)&sf[row][c4 * 4] = f4;
  }
  __syncthreads();
  const int r = tid >> 3;
  const int c0 = (tid & 7) * 24;
  float acc[24];
#pragma unroll
  for (int l = 0; l < 24; ++l) acc[l] = ltb[c0 + l];
#pragma unroll 4
  for (int j = 0; j < 64; ++j) {
    float f = sf[r][j];
#pragma unroll
    for (int l4 = 0; l4 < 6; ++l4) {
      float4 w4 = *(const float4*)&sw[j][c0 + l4 * 4];
      acc[l4 * 4 + 0] = fmaf(f, w4.x, acc[l4 * 4 + 0]);
      acc[l4 * 4 + 1] = fmaf(f, w4.y, acc[l4 * 4 + 1]);
      acc[l4 * 4 + 2] = fmaf(f, w4.z, acc[l4 * 4 + 2]);
      acc[l4 * 4 + 3] = fmaf(f, w4.w, acc[l4 * 4 + 3]);
    }
  }
  float* orow = lt + (size_t)(r0 + r) * 192 + c0;
#pragma unroll
  for (int l4 = 0; l4 < 6; ++l4)
    *(float4*)&orow[l4 * 4] = make_float4(acc[l4 * 4], acc[l4 * 4 + 1],
                                          acc[l4 * 4 + 2], acc[l4 * 4 + 3]);
}

// ---------------------------------------------------------------- K3: main
// one wave per point, lane = channel c.
__global__ __launch_bounds__(256) void k_main(
    const float4* __restrict__ xytp, const float* __restrict__ lt,
    const int* __restrict__ knn, const float* __restrict__ pe_w1,
    const float* __restrict__ pe_b1, const float* __restrict__ pe_w2,
    const float* __restrict__ pe_b2, const float* __restrict__ ln_g,
    const float* __restrict__ ln_b, float* __restrict__ out) {
  __shared__ float s_h[4][16][64];  // 16 KB
  const int lane = threadIdx.x & 63;
  const int wave = threadIdx.x >> 6;
  const int pid = __builtin_amdgcn_readfirstlane(blockIdx.x * 4 + wave);
  const int b = pid >> 13;
  const int n = pid & 8191;

  float w1c[4];
#pragma unroll
  for (int d = 0; d < 4; ++d) w1c[d] = pe_w1[d * 64 + lane];
  const float b1c = pe_b1[lane];
  float w2c[64];
#pragma unroll
  for (int j = 0; j < 64; ++j) w2c[j] = pe_w2[j * 64 + lane];
  const float b2c = pe_b2[lane];
  const float gc = ln_g[lane], bc = ln_b[lane];

  int nb[16];
#pragma unroll
  for (int k = 0; k < 16; ++k) nb[k] = knn[pid * 16 + k];  // uniform s_load

  const float* __restrict__ ltb = lt + (size_t)(b << 13) * 192;
  float psi[16], alp[16];
#pragma unroll
  for (int k = 0; k < 16; ++k) {
    const float* row = ltb + (size_t)nb[k] * 192;
    psi[k] = row[64 + lane];
    alp[k] = row[128 + lane];
  }
  const float vc = ltb[(size_t)n * 192 + lane];

  const float4 q = xytp[(b << 13) + n];
#pragma unroll
  for (int k = 0; k < 16; ++k) {
    float4 g = xytp[(b << 13) + nb[k]];  // uniform s_load
    float r0 = q.x - g.x, r1 = q.y - g.y, r2 = q.z - g.z, r3 = q.w - g.w;
    float h = fmaf(r3, w1c[3],
                   fmaf(r2, w1c[2], fmaf(r1, w1c[1], fmaf(r0, w1c[0], b1c))));
    s_h[wave][k][lane] = fmaxf(h, 0.0f);
  }
  __syncthreads();

  float pre[16], apd[16];
#pragma unroll
  for (int k = 0; k < 16; ++k) {
    float acc = b2c;
#pragma unroll
    for (int j4 = 0; j4 < 16; ++j4) {
      float4 h4 = *(const float4*)&s_h[wave][k][j4 * 4];  // broadcast
      acc = fmaf(h4.x, w2c[j4 * 4 + 0], acc);
      acc = fmaf(h4.y, w2c[j4 * 4 + 1], acc);
      acc = fmaf(h4.z, w2c[j4 * 4 + 2], acc);
      acc = fmaf(h4.w, w2c[j4 * 4 + 3], acc);
    }
    pre[k] = (vc - psi[k]) + acc;
    apd[k] = alp[k] + acc;
  }

  float xk[16], m = -INFINITY;
#pragma unroll
  for (int k = 0; k < 16; ++k) {
    float s = pre[k], ss = pre[k] * pre[k];
#pragma unroll
    for (int d = 1; d < 64; d <<= 1) {
      s += __shfl_xor(s, d);
      ss += __shfl_xor(ss, d);
    }
    float mu = s * 0.015625f;
    float var = fmaf(ss, 0.015625f, -mu * mu);
    float inv = 1.0f / sqrtf(var + 1e-5f);
    float lnv = fmaf((pre[k] - mu) * inv, gc, bc);
    xk[k] = lnv * 0.125f;  // / sqrt(C)
    m = fmaxf(m, xk[k]);
  }
  float se = 0.f, acc = 0.f;
#pragma unroll
  for (int k = 0; k < 16; ++k) {
    float e = __expf(xk[k] - m);
    se += e;
    acc = fmaf(e, apd[k], acc);
  }
  out[(size_t)pid * 64 + lane] = acc / se;
}

// ---------------------------------------------------------------- launch
extern "C" void kernel_launch(void* const* d_in, const int* in_sizes, int n_in,
                              void* d_out, int out_size, void* d_ws,
                              size_t ws_size, hipStream_t stream) {
  const float4* xytp = (const float4*)d_in[0];
  const float* features = (const float*)d_in[1];
  const float* pe_w1 = (const float*)d_in[2];
  const float* pe_b1 = (const float*)d_in[3];
  const float* pe_w2 = (const float*)d_in[4];
  const float* pe_b2 = (const float*)d_in[5];
  const float* lt_w = (const float*)d_in[6];
  const float* lt_b = (const float*)d_in[7];
  const float* ln_g = (const float*)d_in[8];
  const float* ln_b = (const float*)d_in[9];
  float* out = (float*)d_out;

  char* ws = (char*)d_ws;
  float4* cand = (float4*)ws;                             // 524288 B
  int* idxbuf = (int*)(ws + 524288);                      // 2097152 B
  float* lt = (float*)(ws + 524288 + 2097152);            // 25165824 B

  k_prep<<<(BATCH * NPTS) / 256, 256, 0, stream>>>(xytp, cand);
  k_knn<<<BATCH * (NPTS / 64), 128, 0, stream>>>(cand, idxbuf);
  k_lt<<<(BATCH * NPTS) / 32, 256, 0, stream>>>(features, lt_w, lt_b, lt);
  k_main<<<(BATCH * NPTS) / 4, 256, 0, stream>>>(xytp, lt, idxbuf, pe_w1,
                                                 pe_b1, pe_w2, pe_b2, ln_g,
                                                 ln_b, out);
}